// Round 2
// baseline (129.502 us; speedup 1.0000x reference)
//
#include <hip/hip_runtime.h>
#include <math.h>

// Sinkhorn distance, collapsed form — R5: single kernel, last-block epilogue.
//
// Reference math (unchanged from R3, which passed with absmax 0.0):
//   C[n,m] = ||x_n - y_m||,  K = exp(-C/2)
//   u_1 = 1/(T_n + 1e-8)                 where T_n = sum_m K
//   u_k = 1/(S_n/(u_{k-1}+1e-8) + 1e-8)  where S_n = sum_m K*r   (k >= 2)
//   err_k = mean_n |u_k - u_{k-1}|  (u_0 = 1); freeze at first err_k < 0.1
//   out[n] = (u_f/(u_f+1e-8)) * W_n      where W_n = sum_m K*r*C
//
// R4 -> R5: hipLaunchCooperativeKernel is NOT graph-capturable (R4's output
// was all-zeros: absmax == max|ref|). Replaced grid.sync() with the
// deadlock-free last-block pattern: every block writes its partial results
// (err partials, u-sequence, W, S) to ws with plain stores, release-fences
// (__threadfence -> buffer_wbl2/inv sc1, handles cross-XCD L2 per G16),
// then atomicAdd's a counter. The block seeing old==511 acquire-fences and
// runs the epilogue (global err table -> kstar -> all 4096 outputs). No
// block ever waits on an unscheduled block => safe for any dispatch order.
// Counter is zeroed by a 4-byte hipMemsetAsync (capturable; harness itself
// uses memsets) — replaces the whole second kernel dispatch of R3.
//
// Bit-exactness: phase 1 (T/S/W), the u-recurrence expression, and the
// epilogue expression are byte-identical to R3. Only the err-mean summation
// ORDER changes; kstar is ulp-robust (err decays geometrically through 0.1).
//
// ws float-slot layout:
//   [0,      16384)  partial[blk][k]  per-block err partials (512 x 32)
//   [16384,  20480)  Wg[n]
//   [20480,  24576)  Sg[n]            (fallback-path insurance only)
//   [24576, 159744)  u_all[k][n]      k in [0,32], only k>=1 used
//   [159744]         counter (uint)

#define NN 4096
#define MM 512
#define DD 32
#define MAX_ITER 100
#define K_CAP 32
#define THRESH 0.1f
#define NBLK 512   // 8 rows per block

#define PART_OFF 0
#define W_OFF    16384
#define S_OFF    20480
#define U_OFF    24576
#define CNT_OFF  159744

__global__ __launch_bounds__(256) void sink_fused(const float* __restrict__ x,
                                                  const float* __restrict__ y,
                                                  const float* __restrict__ r,
                                                  float* __restrict__ ws,
                                                  float* __restrict__ out) {
    const int t = threadIdx.x;
    const int blk = blockIdx.x;
    const int row0 = blk * 8;

    float* __restrict__ partial = ws + PART_OFF;
    float* __restrict__ Wg = ws + W_OFF;
    float* __restrict__ Sg = ws + S_OFF;
    float* __restrict__ u_all = ws + U_OFF;
    unsigned int* cnt = (unsigned int*)(ws + CNT_OFF);

    // ---------------- phase 1: T,S,W for this block's 8 rows (== R3 k1) ----
    __shared__ float xs[8][32];        // 8 rows of x
    if (t < 64) {
        ((float4*)&xs[0][0])[t] = ((const float4*)(x + row0 * DD))[t];
    }
    __syncthreads();

    const int m1 = t, m2 = t + 256;    // each thread owns 2 y-columns
    float4 y1[8], y2[8];
    const float4* yv1 = (const float4*)(y + m1 * DD);
    const float4* yv2 = (const float4*)(y + m2 * DD);
#pragma unroll
    for (int c = 0; c < 8; ++c) { y1[c] = yv1[c]; y2[c] = yv2[c]; }

    float pT[8], pS[8], pW[8];
#pragma unroll
    for (int i = 0; i < 8; ++i) {
        float d2a = 0.f, d2b = 0.f;
#pragma unroll
        for (int c = 0; c < 8; ++c) {
            float4 xv = ((const float4*)&xs[i][0])[c];
            float dx;
            dx = xv.x - y1[c].x; d2a += dx * dx;
            dx = xv.y - y1[c].y; d2a += dx * dx;
            dx = xv.z - y1[c].z; d2a += dx * dx;
            dx = xv.w - y1[c].w; d2a += dx * dx;
            dx = xv.x - y2[c].x; d2b += dx * dx;
            dx = xv.y - y2[c].y; d2b += dx * dx;
            dx = xv.z - y2[c].z; d2b += dx * dx;
            dx = xv.w - y2[c].w; d2b += dx * dx;
        }
        float Ca = sqrtf(d2a), Cb = sqrtf(d2b);
        float Ka = __expf(-0.5f * Ca), Kb = __expf(-0.5f * Cb);
        float ra = r[(row0 + i) * MM + m1];
        float rb = r[(row0 + i) * MM + m2];
        pT[i] = Ka + Kb;
        pS[i] = Ka * ra + Kb * rb;
        pW[i] = Ka * ra * Ca + Kb * rb * Cb;
    }

    // reduce (T,S,W) over 256 threads: wave shuffle + LDS across 4 waves
    __shared__ float red[4][8][3];
    const int wave = t >> 6, lane = t & 63;
#pragma unroll
    for (int i = 0; i < 8; ++i) {
#pragma unroll
        for (int s = 32; s > 0; s >>= 1) {
            pT[i] += __shfl_down(pT[i], s, 64);
            pS[i] += __shfl_down(pS[i], s, 64);
            pW[i] += __shfl_down(pW[i], s, 64);
        }
        if (lane == 0) {
            red[wave][i][0] = pT[i];
            red[wave][i][1] = pS[i];
            red[wave][i][2] = pW[i];
        }
    }
    __syncthreads();

    __shared__ float Tn[8], Sv[8], Wn[8];
    if (t < 8) {
        float sT = 0.f, sS = 0.f, sW = 0.f;
#pragma unroll
        for (int w = 0; w < 4; ++w) {
            sT += red[w][t][0];
            sS += red[w][t][1];
            sW += red[w][t][2];
        }
        Tn[t] = sT;
        Sv[t] = sS;
        Wn[t] = sW;
    }
    __syncthreads();

    // ---------------- phase 2: local u-recurrence, k = 1..K_CAP ------------
    // thread i<8 owns row i; full u_k sequence kept (no replay later)
    __shared__ float useq[8][K_CAP + 1];   // useq[i][k] = u_k, k in [1,K_CAP]
    __shared__ float du[8][K_CAP];         // du[i][k-1] = |u_k - u_{k-1}|
    if (t < 8) {
        float u = 1.0f / (Tn[t] + 1e-8f);
        useq[t][1] = u;
        du[t][0] = fabsf(u - 1.0f);
        const float Sr = Sv[t];
        for (int k = 2; k <= K_CAP; ++k) {
            const float un = 1.0f / (Sr / (u + 1e-8f) + 1e-8f);
            du[t][k - 1] = fabsf(un - u);
            u = un;
            useq[t][k] = u;
        }
    }
    __syncthreads();

    // publish this block's contribution to ws (plain stores)
    if (t < K_CAP) {
        float e = 0.f;
#pragma unroll
        for (int i = 0; i < 8; ++i) e += du[i][t];
        partial[blk * K_CAP + t] = e;
    }
    {   // u-sequence: 256 threads -> 256 (row,k) pairs, coalesced in n
        const int i = t & 7, kk = t >> 3;           // kk in [0,31] -> k=kk+1
        u_all[(kk + 1) * NN + row0 + i] = useq[i][kk + 1];
    }
    if (t < 8) {
        Wg[row0 + t] = Wn[t];
        Sg[row0 + t] = Sv[t];
    }

    // release: make this block's ws writes device-visible, then count in
    __threadfence();
    __syncthreads();
    __shared__ int lastFlag;
    if (t == 0) {
        unsigned int old = atomicAdd(cnt, 1u);
        lastFlag = (old == (unsigned int)(NBLK - 1)) ? 1 : 0;
    }
    __syncthreads();
    if (!lastFlag) return;

    // ---------------- phase 3 (last block only): errk, kstar, outputs ------
    __threadfence();   // acquire: invalidate caches before reading peers' data

    __shared__ float ered[8][K_CAP];
    {
        const int k = t & 31, chunk = t >> 5;       // 8 chunks x 64 blocks
        float e = 0.f;
        const int b0 = chunk * (NBLK / 8);
        for (int b = b0; b < b0 + NBLK / 8; ++b) e += partial[b * K_CAP + k];
        ered[chunk][k] = e;
    }
    __syncthreads();
    __shared__ float errk[K_CAP];
    if (t < K_CAP) {
        float e = 0.f;
#pragma unroll
        for (int c = 0; c < 8; ++c) e += ered[c][t];
        errk[t] = e * (1.0f / NN);
    }
    __syncthreads();

    // first k with err_k < THRESH (guaranteed <= K_CAP; MAX_ITER fallback)
    int kstar = MAX_ITER;
    for (int k = K_CAP; k >= 1; --k) {
        if (errk[k - 1] < THRESH) kstar = k;
    }

    if (kstar <= K_CAP) {
        const float* __restrict__ urow = u_all + kstar * NN;
#pragma unroll
        for (int j = 0; j < 16; ++j) {
            const int n = j * 256 + t;
            const float u = urow[n];
            out[n] = (u / (u + 1e-8f)) * Wg[n];
        }
    } else {           // never taken (err_32 ~ 1e-20) — insurance only
        for (int j = 0; j < 16; ++j) {
            const int n = j * 256 + t;
            float u = u_all[K_CAP * NN + n];
            const float Sr = Sg[n];
            for (int k = K_CAP + 1; k <= kstar; ++k) {
                u = 1.0f / (Sr / (u + 1e-8f) + 1e-8f);
            }
            out[n] = (u / (u + 1e-8f)) * Wg[n];
        }
    }
}

extern "C" void kernel_launch(void* const* d_in, const int* in_sizes, int n_in,
                              void* d_out, int out_size, void* d_ws, size_t ws_size,
                              hipStream_t stream) {
    const float* x = (const float*)d_in[0];   // [4096,32]
    const float* y = (const float*)d_in[1];   // [512,32]
    const float* r = (const float*)d_in[2];   // [4096,512]
    float* outp = (float*)d_out;              // [4096]
    float* ws = (float*)d_ws;

    // zero the arrival counter (ws is poisoned between iterations)
    hipMemsetAsync((char*)d_ws + CNT_OFF * sizeof(float), 0, 4, stream);
    sink_fused<<<NBLK, 256, 0, stream>>>(x, y, r, ws, outp);
}